// Round 1
// baseline (427.725 us; speedup 1.0000x reference)
//
#include <hip/hip_runtime.h>

#define B_  8
#define C_  64
#define OC_ 64
#define H_  256
#define W_  256
#define HW_ (H_ * W_)

// One block per (b,h) row, one thread per w column.
// Fully fused: offset conv + mask conv + sigmoid + bilinear sample + 1x1 conv.
__global__ __launch_bounds__(256) void dcn_fused(
    const float* __restrict__ x,
    const float* __restrict__ w_conv,
    const float* __restrict__ w_off,
    const float* __restrict__ b_off,
    const float* __restrict__ w_mask,
    const float* __restrict__ b_mask,
    float* __restrict__ out)
{
    const int g   = blockIdx.x;
    // XCD-aware swizzle: 2048 rows / 8 XCDs = 256 contiguous rows per XCD
    // (== exactly one batch image per XCD -> L2 row reuse for sampling).
    const int row = (g & 7) * (B_ * H_ / 8) + (g >> 3);
    const int b   = row >> 8;          // row / H_
    const int h   = row & (H_ - 1);
    const int w   = threadIdx.x;

    // ---- Phase 1: offset / mask logits (dot products over channels) ----
    const float* __restrict__ xp = x + (size_t)b * C_ * HW_ + h * W_ + w;
    float oy = b_off[0];
    float ox = b_off[1];
    float ml = b_mask[0];
#pragma unroll 8
    for (int c = 0; c < C_; ++c) {
        const float v = xp[(size_t)c * HW_];
        oy = fmaf(w_off[c],      v, oy);   // w_off[0][c] -> dy
        ox = fmaf(w_off[C_ + c], v, ox);   // w_off[1][c] -> dx
        ml = fmaf(w_mask[c],     v, ml);
    }
    const float m = 1.0f / (1.0f + __expf(-ml));   // sigmoid

    // ---- Phase 2: bilinear setup (valid & mask folded into 4 weights) ----
    const float py  = (float)h + oy;
    const float px  = (float)w + ox;
    const float y0f = floorf(py);
    const float x0f = floorf(px);
    const float wy1 = py - y0f, wx1 = px - x0f;
    const float wy0 = 1.0f - wy1, wx0 = 1.0f - wx1;
    const int y0 = (int)y0f, x0 = (int)x0f;
    const int y1 = y0 + 1,   x1 = x0 + 1;
    const float vy0 = (y0 >= 0 && y0 < H_) ? 1.0f : 0.0f;
    const float vy1 = (y1 >= 0 && y1 < H_) ? 1.0f : 0.0f;
    const float vx0 = (x0 >= 0 && x0 < W_) ? 1.0f : 0.0f;
    const float vx1 = (x1 >= 0 && x1 < W_) ? 1.0f : 0.0f;
    const int y0c = min(max(y0, 0), H_ - 1);
    const int y1c = min(max(y1, 0), H_ - 1);
    const int x0c = min(max(x0, 0), W_ - 1);
    const int x1c = min(max(x1, 0), W_ - 1);
    const float w00 = wy0 * wx0 * vy0 * vx0 * m;
    const float w01 = wy0 * wx1 * vy0 * vx1 * m;
    const float w10 = wy1 * wx0 * vy1 * vx0 * m;
    const float w11 = wy1 * wx1 * vy1 * vx1 * m;
    const int i00 = y0c * W_ + x0c;
    const int i01 = y0c * W_ + x1c;
    const int i10 = y1c * W_ + x0c;
    const int i11 = y1c * W_ + x1c;

    // ---- Phase 3: masked bilinear sample for all channels ----
    const float* __restrict__ xb = x + (size_t)b * C_ * HW_;
    float s[C_];
#pragma unroll 8
    for (int c = 0; c < C_; ++c) {
        const float* __restrict__ xc = xb + (size_t)c * HW_;
        s[c] = w00 * xc[i00] + w01 * xc[i01] + w10 * xc[i10] + w11 * xc[i11];
    }

    // ---- Phase 4: 64x64 1x1 conv; w_conv rows are wave-uniform (scalar loads) ----
    float* __restrict__ op = out + (size_t)b * OC_ * HW_ + h * W_ + w;
#pragma unroll 4
    for (int oc = 0; oc < OC_; ++oc) {
        const float* __restrict__ wr = w_conv + oc * C_;
        float acc = 0.0f;
#pragma unroll
        for (int c = 0; c < C_; ++c) acc = fmaf(wr[c], s[c], acc);
        op[(size_t)oc * HW_] = acc;
    }
}

extern "C" void kernel_launch(void* const* d_in, const int* in_sizes, int n_in,
                              void* d_out, int out_size, void* d_ws, size_t ws_size,
                              hipStream_t stream) {
    const float* x      = (const float*)d_in[0];
    const float* w_conv = (const float*)d_in[1];
    const float* w_off  = (const float*)d_in[2];
    const float* b_off  = (const float*)d_in[3];
    const float* w_mask = (const float*)d_in[4];
    const float* b_mask = (const float*)d_in[5];
    float* out = (float*)d_out;

    dcn_fused<<<dim3(B_ * H_), dim3(256), 0, stream>>>(
        x, w_conv, w_off, b_off, w_mask, b_mask, out);
}

// Round 2
// 359.777 us; speedup vs baseline: 1.1889x; 1.1889x over previous
//
#include <hip/hip_runtime.h>

#define B_  8
#define C_  64
#define OC_ 64
#define H_  256
#define W_  256
#define HW_ (H_ * W_)

typedef __attribute__((ext_vector_type(8))) short bf16x8;   // 8 bf16 in 4 VGPRs
typedef __attribute__((ext_vector_type(4))) float f32x4;

__device__ __forceinline__ unsigned short f2bf(float f) {
    // round-to-nearest-even fp32 -> bf16
    unsigned int u = __float_as_uint(f);
    u += 0x7fffu + ((u >> 16) & 1u);
    return (unsigned short)(u >> 16);
}

// One block per (b,h) row, thread = w column for phases 1-3.
// Phase 4 (64x64 1x1 conv over 256 px) = 64x64x256 GEMM on MFMA:
//   Out[oc][px] = sum_c W[oc][c] * S[c][px],  bf16 in / fp32 acc.
__global__ __launch_bounds__(256) void dcn_fused(
    const float* __restrict__ x,
    const float* __restrict__ w_conv,
    const float* __restrict__ w_off,
    const float* __restrict__ b_off,
    const float* __restrict__ w_mask,
    const float* __restrict__ b_mask,
    float* __restrict__ out)
{
    const int g   = blockIdx.x;
    // XCD swizzle: 2048 rows / 8 XCDs -> one batch image per XCD (L2 reuse).
    const int row = (g & 7) * (B_ * H_ / 8) + (g >> 3);
    const int b   = row >> 8;
    const int h   = row & (H_ - 1);
    const int w   = threadIdx.x;

    // ---- Phase 1: offset / mask logits ----
    const float* __restrict__ xp = x + (size_t)b * C_ * HW_ + h * W_ + w;
    float oy = b_off[0];
    float ox = b_off[1];
    float ml = b_mask[0];
#pragma unroll 8
    for (int c = 0; c < C_; ++c) {
        const float v = xp[(size_t)c * HW_];
        oy = fmaf(w_off[c],      v, oy);
        ox = fmaf(w_off[C_ + c], v, ox);
        ml = fmaf(w_mask[c],     v, ml);
    }
    const float m = 1.0f / (1.0f + __expf(-ml));

    // ---- Phase 2: bilinear setup (validity & mask folded into corner weights) ----
    const float py  = (float)h + oy;
    const float px_ = (float)w + ox;
    const float y0f = floorf(py);
    const float x0f = floorf(px_);
    const float wy1 = py - y0f, wx1 = px_ - x0f;
    const float wy0 = 1.0f - wy1, wx0 = 1.0f - wx1;
    const int y0 = (int)y0f, x0 = (int)x0f;
    const int y1 = y0 + 1,   x1 = x0 + 1;
    const float vy0 = (y0 >= 0 && y0 < H_) ? 1.0f : 0.0f;
    const float vy1 = (y1 >= 0 && y1 < H_) ? 1.0f : 0.0f;
    const float vx0 = (x0 >= 0 && x0 < W_) ? 1.0f : 0.0f;
    const float vx1 = (x1 >= 0 && x1 < W_) ? 1.0f : 0.0f;
    const int y0c = min(max(y0, 0), H_ - 1);
    const int y1c = min(max(y1, 0), H_ - 1);
    const int x0c = min(max(x0, 0), W_ - 1);
    const int x1c = min(max(x1, 0), W_ - 1);
    const float w00 = wy0 * wx0 * vy0 * vx0 * m;
    const float w01 = wy0 * wx1 * vy0 * vx1 * m;
    const float w10 = wy1 * wx0 * vy1 * vx0 * m;
    const float w11 = wy1 * wx1 * vy1 * vx1 * m;
    const int i00 = y0c * W_ + x0c;
    const int i01 = y0c * W_ + x1c;
    const int i10 = y1c * W_ + x0c;
    const int i11 = y1c * W_ + x1c;

    // ---- Phase 3: masked bilinear sample, all 64 channels ----
    const float* __restrict__ xb = x + (size_t)b * C_ * HW_;
    float s[C_];
#pragma unroll 8
    for (int c = 0; c < C_; ++c) {
        const float* __restrict__ xc = xb + (size_t)c * HW_;
        s[c] = w00 * xc[i00] + w01 * xc[i01] + w10 * xc[i10] + w11 * xc[i11];
    }

    // ---- Stage S^T[px][c] as bf16 in LDS, XOR-swizzled 16B blocks ----
    // row pitch = 64 bf16 = 128 B = 8 blocks of 16 B; slot = (cblk ^ (px&7)).
    __shared__ uint4 lds[256 * 8];   // 32 KB
    {
        const int pxa = threadIdx.x;
#pragma unroll
        for (int j = 0; j < 8; ++j) {
            uint4 u;
            u.x = (unsigned)f2bf(s[8*j+0]) | ((unsigned)f2bf(s[8*j+1]) << 16);
            u.y = (unsigned)f2bf(s[8*j+2]) | ((unsigned)f2bf(s[8*j+3]) << 16);
            u.z = (unsigned)f2bf(s[8*j+4]) | ((unsigned)f2bf(s[8*j+5]) << 16);
            u.w = (unsigned)f2bf(s[8*j+6]) | ((unsigned)f2bf(s[8*j+7]) << 16);
            lds[pxa * 8 + (j ^ (pxa & 7))] = u;
        }
    }
    __syncthreads();

    // ---- Phase 4: GEMM via mfma_f32_16x16x32_bf16 ----
    // Wave wv handles px in [64*wv, 64*wv+64): 4 N-tiles x 4 M-tiles, K = 64 (2 steps).
    const int lane = threadIdx.x & 63;
    const int wv   = threadIdx.x >> 6;
    const int lrow = lane >> 4;   // 0..3
    const int lcol = lane & 15;

    // A fragments: W[oc][c] from global (L2-resident), fp32 -> bf16.
    // lane holds A[m=lcol][k=lrow*8+j], j=0..7 -> 8 consecutive c.
    bf16x8 afrag[4][2];
#pragma unroll
    for (int mt = 0; mt < 4; ++mt) {
#pragma unroll
        for (int kk = 0; kk < 2; ++kk) {
            const int oc = mt * 16 + lcol;
            const int c0 = kk * 32 + lrow * 8;
            const float4* wp = (const float4*)(w_conv + oc * C_ + c0);
            const float4 lo = wp[0];
            const float4 hi = wp[1];
            bf16x8 a;
            a[0] = (short)f2bf(lo.x); a[1] = (short)f2bf(lo.y);
            a[2] = (short)f2bf(lo.z); a[3] = (short)f2bf(lo.w);
            a[4] = (short)f2bf(hi.x); a[5] = (short)f2bf(hi.y);
            a[6] = (short)f2bf(hi.z); a[7] = (short)f2bf(hi.w);
            afrag[mt][kk] = a;
        }
    }

    f32x4 acc[4][4];
#pragma unroll
    for (int mt = 0; mt < 4; ++mt)
#pragma unroll
        for (int nt = 0; nt < 4; ++nt)
            acc[mt][nt] = (f32x4){0.f, 0.f, 0.f, 0.f};

#pragma unroll
    for (int nt = 0; nt < 4; ++nt) {
        const int px = wv * 64 + nt * 16 + lcol;     // B: n = lcol
#pragma unroll
        for (int kk = 0; kk < 2; ++kk) {
            const int cblk = kk * 4 + lrow;          // B: k = lrow*8+j
            union { uint4 u; bf16x8 v; } bb;
            bb.u = lds[px * 8 + (cblk ^ (px & 7))];
#pragma unroll
            for (int mt = 0; mt < 4; ++mt)
                acc[mt][nt] = __builtin_amdgcn_mfma_f32_16x16x32_bf16(
                    afrag[mt][kk], bb.v, acc[mt][nt], 0, 0, 0);
        }
    }

    // ---- Epilogue: C/D layout col=lane&15, row=(lane>>4)*4+r ----
    float* __restrict__ ob = out + (size_t)b * OC_ * HW_ + h * W_;
#pragma unroll
    for (int mt = 0; mt < 4; ++mt) {
        const int ocb = mt * 16 + lrow * 4;
#pragma unroll
        for (int nt = 0; nt < 4; ++nt) {
            const int px = wv * 64 + nt * 16 + lcol;
            const f32x4 a = acc[mt][nt];
#pragma unroll
            for (int r = 0; r < 4; ++r)
                ob[(size_t)(ocb + r) * HW_ + px] = a[r];
        }
    }
}

extern "C" void kernel_launch(void* const* d_in, const int* in_sizes, int n_in,
                              void* d_out, int out_size, void* d_ws, size_t ws_size,
                              hipStream_t stream) {
    const float* x      = (const float*)d_in[0];
    const float* w_conv = (const float*)d_in[1];
    const float* w_off  = (const float*)d_in[2];
    const float* b_off  = (const float*)d_in[3];
    const float* w_mask = (const float*)d_in[4];
    const float* b_mask = (const float*)d_in[5];
    float* out = (float*)d_out;

    dcn_fused<<<dim3(B_ * H_), dim3(256), 0, stream>>>(
        x, w_conv, w_off, b_off, w_mask, b_mask, out);
}

// Round 3
// 312.080 us; speedup vs baseline: 1.3706x; 1.1528x over previous
//
#include <hip/hip_runtime.h>

#define B_  8
#define C_  64
#define OC_ 64
#define H_  256
#define W_  256
#define HW_ (H_ * W_)

typedef __attribute__((ext_vector_type(8))) short bf16x8;   // 8 bf16 in 4 VGPRs
typedef __attribute__((ext_vector_type(4))) float f32x4;

__device__ __forceinline__ unsigned short f2bf(float f) {
    unsigned int u = __float_as_uint(f);
    u += 0x7fffu + ((u >> 16) & 1u);     // round-to-nearest-even
    return (unsigned short)(u >> 16);
}

// One block per (b,h) row, thread = w column for phases 1-3.
// Phase 4: 64x64x256 GEMM on MFMA, split into two 32-oc halves to keep
// acc live-range at 32 regs (round-2 post-mortem: VGPR80 + AGPR64 = 144
// unified regs -> 3 waves/SIMD; this caps total at ~<=102 -> 5 waves/SIMD).
__global__ __launch_bounds__(256, 5) void dcn_fused(
    const float* __restrict__ x,
    const float* __restrict__ w_conv,
    const float* __restrict__ w_off,
    const float* __restrict__ b_off,
    const float* __restrict__ w_mask,
    const float* __restrict__ b_mask,
    float* __restrict__ out)
{
    const int g   = blockIdx.x;
    // XCD swizzle: one batch image per XCD -> L2 row reuse for sampling.
    const int row = (g & 7) * (B_ * H_ / 8) + (g >> 3);
    const int b   = row >> 8;
    const int h   = row & (H_ - 1);
    const int w   = threadIdx.x;

    // ---- Phase 1: offset / mask logits ----
    const float* __restrict__ xp = x + (size_t)b * C_ * HW_ + h * W_ + w;
    float oy = b_off[0];
    float ox = b_off[1];
    float ml = b_mask[0];
#pragma unroll 8
    for (int c = 0; c < C_; ++c) {
        const float v = xp[(size_t)c * HW_];
        oy = fmaf(w_off[c],      v, oy);
        ox = fmaf(w_off[C_ + c], v, ox);
        ml = fmaf(w_mask[c],     v, ml);
    }
    const float m = 1.0f / (1.0f + __expf(-ml));

    // ---- Phase 2: bilinear setup ----
    const float py  = (float)h + oy;
    const float px_ = (float)w + ox;
    const float y0f = floorf(py);
    const float x0f = floorf(px_);
    const float wy1 = py - y0f, wx1 = px_ - x0f;
    const float wy0 = 1.0f - wy1, wx0 = 1.0f - wx1;
    const int y0 = (int)y0f, x0 = (int)x0f;
    const int y1 = y0 + 1,   x1 = x0 + 1;
    const float vy0 = (y0 >= 0 && y0 < H_) ? 1.0f : 0.0f;
    const float vy1 = (y1 >= 0 && y1 < H_) ? 1.0f : 0.0f;
    const float vx0 = (x0 >= 0 && x0 < W_) ? 1.0f : 0.0f;
    const float vx1 = (x1 >= 0 && x1 < W_) ? 1.0f : 0.0f;
    const int y0c = min(max(y0, 0), H_ - 1);
    const int y1c = min(max(y1, 0), H_ - 1);
    const int x0c = min(max(x0, 0), W_ - 1);
    const int x1c = min(max(x1, 0), W_ - 1);
    const float w00 = wy0 * wx0 * vy0 * vx0 * m;
    const float w01 = wy0 * wx1 * vy0 * vx1 * m;
    const float w10 = wy1 * wx0 * vy1 * vx0 * m;
    const float w11 = wy1 * wx1 * vy1 * vx1 * m;
    const int i00 = y0c * W_ + x0c;
    const int i01 = y0c * W_ + x1c;
    const int i10 = y1c * W_ + x0c;
    const int i11 = y1c * W_ + x1c;

    // ---- Phase 3: masked bilinear sample, streamed to LDS in 8-ch chunks ----
    // (keeps only 8 s-values live -> low VGPR pressure)
    __shared__ uint4 lds[256 * 8];   // S^T[px][c] bf16, 32 KB, XOR-swizzled 16B blocks
    const float* __restrict__ xb = x + (size_t)b * C_ * HW_;
    const int pxa = threadIdx.x;
#pragma unroll
    for (int j = 0; j < 8; ++j) {
        float sv[8];
#pragma unroll
        for (int t = 0; t < 8; ++t) {
            const float* __restrict__ xc = xb + (size_t)(8 * j + t) * HW_;
            sv[t] = w00 * xc[i00] + w01 * xc[i01] + w10 * xc[i10] + w11 * xc[i11];
        }
        uint4 u;
        u.x = (unsigned)f2bf(sv[0]) | ((unsigned)f2bf(sv[1]) << 16);
        u.y = (unsigned)f2bf(sv[2]) | ((unsigned)f2bf(sv[3]) << 16);
        u.z = (unsigned)f2bf(sv[4]) | ((unsigned)f2bf(sv[5]) << 16);
        u.w = (unsigned)f2bf(sv[6]) | ((unsigned)f2bf(sv[7]) << 16);
        lds[pxa * 8 + (j ^ (pxa & 7))] = u;
    }
    __syncthreads();

    // ---- Phase 4: GEMM via mfma_f32_16x16x32_bf16, two 32-oc halves ----
    const int lane = threadIdx.x & 63;
    const int wv   = threadIdx.x >> 6;
    const int lrow = lane >> 4;   // 0..3
    const int lcol = lane & 15;

    float* __restrict__ ob = out + (size_t)b * OC_ * HW_ + h * W_;

#pragma unroll
    for (int half = 0; half < 2; ++half) {
        // A fragments for this half: W[oc][c], fp32 -> bf16 (L2-hot).
        // lane holds A[m=lcol][k=lrow*8+j]
        bf16x8 afrag[2][2];
#pragma unroll
        for (int mtl = 0; mtl < 2; ++mtl) {
#pragma unroll
            for (int kk = 0; kk < 2; ++kk) {
                const int oc = (half * 2 + mtl) * 16 + lcol;
                const int c0 = kk * 32 + lrow * 8;
                const float4* wp = (const float4*)(w_conv + oc * C_ + c0);
                const float4 lo = wp[0];
                const float4 hi = wp[1];
                bf16x8 a;
                a[0] = (short)f2bf(lo.x); a[1] = (short)f2bf(lo.y);
                a[2] = (short)f2bf(lo.z); a[3] = (short)f2bf(lo.w);
                a[4] = (short)f2bf(hi.x); a[5] = (short)f2bf(hi.y);
                a[6] = (short)f2bf(hi.z); a[7] = (short)f2bf(hi.w);
                afrag[mtl][kk] = a;
            }
        }

        f32x4 acc[2][4];
#pragma unroll
        for (int mtl = 0; mtl < 2; ++mtl)
#pragma unroll
            for (int nt = 0; nt < 4; ++nt)
                acc[mtl][nt] = (f32x4){0.f, 0.f, 0.f, 0.f};

#pragma unroll
        for (int nt = 0; nt < 4; ++nt) {
            const int px = wv * 64 + nt * 16 + lcol;     // B: n = lcol
#pragma unroll
            for (int kk = 0; kk < 2; ++kk) {
                const int cblk = kk * 4 + lrow;          // B: k = lrow*8+j
                union { uint4 u; bf16x8 v; } bb;
                bb.u = lds[px * 8 + (cblk ^ (px & 7))];
#pragma unroll
                for (int mtl = 0; mtl < 2; ++mtl)
                    acc[mtl][nt] = __builtin_amdgcn_mfma_f32_16x16x32_bf16(
                        afrag[mtl][kk], bb.v, acc[mtl][nt], 0, 0, 0);
            }
        }

        // Epilogue: C/D layout col=lane&15, row=(lane>>4)*4+r
#pragma unroll
        for (int mtl = 0; mtl < 2; ++mtl) {
            const int ocb = (half * 2 + mtl) * 16 + lrow * 4;
#pragma unroll
            for (int nt = 0; nt < 4; ++nt) {
                const int px = wv * 64 + nt * 16 + lcol;
                const f32x4 a = acc[mtl][nt];
#pragma unroll
                for (int r = 0; r < 4; ++r)
                    ob[(size_t)(ocb + r) * HW_ + px] = a[r];
            }
        }
    }
}

extern "C" void kernel_launch(void* const* d_in, const int* in_sizes, int n_in,
                              void* d_out, int out_size, void* d_ws, size_t ws_size,
                              hipStream_t stream) {
    const float* x      = (const float*)d_in[0];
    const float* w_conv = (const float*)d_in[1];
    const float* w_off  = (const float*)d_in[2];
    const float* b_off  = (const float*)d_in[3];
    const float* w_mask = (const float*)d_in[4];
    const float* b_mask = (const float*)d_in[5];
    float* out = (float*)d_out;

    dcn_fused<<<dim3(B_ * H_), dim3(256), 0, stream>>>(
        x, w_conv, w_off, b_off, w_mask, b_mask, out);
}